// Round 1
// baseline (364.275 us; speedup 1.0000x reference)
//
#include <hip/hip_runtime.h>
#include <math.h>

#define CCH 256      // channels C
#define OCH 50       // output channels O
#define NPIX 16384   // H*W
#define BATCH 4
#define BO (BATCH*OCH)   // 200
#define NSPLIT 128       // K-split for S GEMM
#define KCHUNK (NPIX/NSPLIT)  // 128 n per block
#define NSUB 32

// ---------- K0: transpose W_f [O,C] -> WfT [C,O] ----------
__global__ void k0_transpose(const float* __restrict__ Wf, float* __restrict__ WfT) {
    int i = blockIdx.x * 256 + threadIdx.x;
    if (i < OCH * CCH) {
        int o = i / CCH, c = i % CCH;
        WfT[c * OCH + o] = Wf[i];
    }
}

// ---------- K1: F[b,o,n] = sum_c WfT[c,o] * x[b,c,n] ----------
__global__ __launch_bounds__(256) void k1_F(const float* __restrict__ x,
                                            const float* __restrict__ WfT,
                                            float* __restrict__ F) {
    int b = blockIdx.y;
    int n = blockIdx.x * 256 + threadIdx.x;
    float acc[OCH];
#pragma unroll
    for (int o = 0; o < OCH; ++o) acc[o] = 0.f;
    const float* xp = x + (size_t)b * CCH * NPIX + n;
#pragma unroll 4
    for (int c = 0; c < CCH; ++c) {
        float xv = xp[(size_t)c * NPIX];
        const float* w = WfT + c * OCH;   // uniform -> s_load
#pragma unroll
        for (int o = 0; o < OCH; ++o) acc[o] = fmaf(w[o], xv, acc[o]);
    }
    float* Fp = F + (size_t)b * OCH * NPIX + n;
#pragma unroll
    for (int o = 0; o < OCH; ++o) Fp[(size_t)o * NPIX] = acc[o];
}

// ---------- K2: Spart[ks, b*O+o, c] = sum_{n in chunk} F[b,o,n]*x[b,c,n] ----------
__global__ __launch_bounds__(256) void k2_Spart(const float* __restrict__ x,
                                                const float* __restrict__ F,
                                                float* __restrict__ Spart) {
    int ks = blockIdx.x;          // 0..NSPLIT-1
    int b  = blockIdx.y;
    int tid = threadIdx.x;        // = c
    __shared__ float xl[NSUB * (CCH + 1)];  // [n][c] transposed, pad -> conflict-free
    float acc[OCH];
#pragma unroll
    for (int o = 0; o < OCH; ++o) acc[o] = 0.f;
    const float* xb = x + (size_t)b * CCH * NPIX;
    const float* Fb = F + (size_t)b * OCH * NPIX;
    int n0 = ks * KCHUNK;
    int ln = tid & 31, cr = tid >> 5;     // staging roles: lane-n, c-row
    for (int sub = 0; sub < KCHUNK / NSUB; ++sub) {
        int ns = n0 + sub * NSUB;
        __syncthreads();
        // stage x[c][ns..ns+31] -> xl[n][c]
        for (int it = 0; it < CCH / 8; ++it) {
            int c = it * 8 + cr;
            xl[ln * (CCH + 1) + c] = xb[(size_t)c * NPIX + ns + ln];
        }
        __syncthreads();
        for (int ng = 0; ng < NSUB / 4; ++ng) {
            float xv0 = xl[(ng * 4 + 0) * (CCH + 1) + tid];
            float xv1 = xl[(ng * 4 + 1) * (CCH + 1) + tid];
            float xv2 = xl[(ng * 4 + 2) * (CCH + 1) + tid];
            float xv3 = xl[(ng * 4 + 3) * (CCH + 1) + tid];
            const float* fp = Fb + ns + ng * 4;
#pragma unroll
            for (int o = 0; o < OCH; ++o) {
                float4 f = *(const float4*)(fp + (size_t)o * NPIX);  // uniform -> s_load
                acc[o] = fmaf(f.x, xv0, acc[o]);
                acc[o] = fmaf(f.y, xv1, acc[o]);
                acc[o] = fmaf(f.z, xv2, acc[o]);
                acc[o] = fmaf(f.w, xv3, acc[o]);
            }
        }
    }
    float* Sp = Spart + ((size_t)ks * BO + (size_t)b * OCH) * CCH + tid;
#pragma unroll
    for (int o = 0; o < OCH; ++o) Sp[(size_t)o * CCH] = acc[o];
}

// ---------- K2r: reduce partials + softmax over c ----------
__global__ __launch_bounds__(256) void k2r_softmax(const float* __restrict__ Spart,
                                                   float* __restrict__ S) {
    int row = blockIdx.x;   // b*O+o, 0..199
    int tid = threadIdx.x;  // c
    __shared__ float red[8];
    float v = 0.f;
    for (int ks = 0; ks < NSPLIT; ++ks)
        v += Spart[((size_t)ks * BO + row) * CCH + tid];
    // block max
    float m = v;
#pragma unroll
    for (int off = 32; off > 0; off >>= 1) m = fmaxf(m, __shfl_xor(m, off, 64));
    if ((tid & 63) == 0) red[tid >> 6] = m;
    __syncthreads();
    m = fmaxf(fmaxf(red[0], red[1]), fmaxf(red[2], red[3]));
    float e = expf(v - m);
    float s = e;
#pragma unroll
    for (int off = 32; off > 0; off >>= 1) s += __shfl_xor(s, off, 64);
    if ((tid & 63) == 0) red[4 + (tid >> 6)] = s;
    __syncthreads();
    float tot = red[4] + red[5] + red[6] + red[7];
    S[(size_t)row * CCH + tid] = e / tot;
}

// ---------- K3: Mt[b*O+o, d] = sum_c Wbeta[d,c] * S[b*O+o, c] ----------
__global__ __launch_bounds__(256) void k3_M(const float* __restrict__ Wbeta,
                                            const float* __restrict__ S,
                                            float* __restrict__ Mt) {
    int row = blockIdx.x;   // b*O+o
    int d = threadIdx.x;
    const float* srow = S + (size_t)row * CCH;
    const float4* wb = (const float4*)(Wbeta + (size_t)d * CCH);
    float acc = 0.f;
#pragma unroll 4
    for (int cg = 0; cg < CCH / 4; ++cg) {
        float4 w = wb[cg];
        float4 s = *(const float4*)(srow + cg * 4);   // uniform -> s_load
        acc += w.x * s.x + w.y * s.y + w.z * s.z + w.w * s.w;
    }
    Mt[(size_t)row * CCH + d] = acc;
}

// ---------- K4: out[b,d,n] = sum_o Mt[b*O+o, d] * F[b,o,n] + x[b,d,n] ----------
__global__ __launch_bounds__(256) void k4_out(const float* __restrict__ x,
                                              const float* __restrict__ F,
                                              const float* __restrict__ Mt,
                                              float* __restrict__ out) {
    int b  = blockIdx.z;
    int dq = blockIdx.y;                       // 0..3 -> 64 d each
    int n  = blockIdx.x * 256 + threadIdx.x;   // 64 chunks
    float acc[64];
#pragma unroll
    for (int dd = 0; dd < 64; ++dd) acc[dd] = 0.f;
    const float* Fp = F + (size_t)b * OCH * NPIX + n;
    const float* mt = Mt + (size_t)b * OCH * CCH + dq * 64;
#pragma unroll 2
    for (int o = 0; o < OCH; ++o) {
        float fo = Fp[(size_t)o * NPIX];
        const float* m = mt + o * CCH;          // uniform -> s_load
#pragma unroll
        for (int dd = 0; dd < 64; ++dd) acc[dd] = fmaf(m[dd], fo, acc[dd]);
    }
    const float* xp = x + ((size_t)b * CCH + dq * 64) * NPIX + n;
    float* op = out + ((size_t)b * CCH + dq * 64) * NPIX + n;
#pragma unroll
    for (int dd = 0; dd < 64; ++dd)
        op[(size_t)dd * NPIX] = acc[dd] + xp[(size_t)dd * NPIX];
}

extern "C" void kernel_launch(void* const* d_in, const int* in_sizes, int n_in,
                              void* d_out, int out_size, void* d_ws, size_t ws_size,
                              hipStream_t stream) {
    const float* x     = (const float*)d_in[0];   // [4,256,128,128]
    const float* Wf    = (const float*)d_in[1];   // [50,256]
    const float* Wbeta = (const float*)d_in[2];   // [256,256]
    float* out = (float*)d_out;

    // ws layout (floats): F [B*O*NPIX] | WfT [C*O] | S [B*O*C] | Mt [B*O*C]
    float* F   = (float*)d_ws;
    float* WfT = F + (size_t)BATCH * OCH * NPIX;
    float* S   = WfT + CCH * OCH;
    float* Mt  = S + (size_t)BO * CCH;
    // S-partials live in d_out (free until K4 overwrites it)
    float* Spart = out;

    k0_transpose<<<dim3((OCH * CCH + 255) / 256), dim3(256), 0, stream>>>(Wf, WfT);
    k1_F<<<dim3(NPIX / 256, BATCH), dim3(256), 0, stream>>>(x, WfT, F);
    k2_Spart<<<dim3(NSPLIT, BATCH), dim3(256), 0, stream>>>(x, F, Spart);
    k2r_softmax<<<dim3(BO), dim3(256), 0, stream>>>(Spart, S);
    k3_M<<<dim3(BO), dim3(256), 0, stream>>>(Wbeta, S, Mt);
    k4_out<<<dim3(NPIX / 256, 4, BATCH), dim3(256), 0, stream>>>(x, F, Mt, out);
}

// Round 2
// 303.035 us; speedup vs baseline: 1.2021x; 1.2021x over previous
//
#include <hip/hip_runtime.h>
#include <math.h>

#define CCH 256      // channels C
#define OCH 50       // output channels O
#define NPIX 16384   // H*W
#define BATCH 4
#define BO (BATCH*OCH)   // 200
#define NSPLIT 256       // K-split for S GEMM
#define KCHUNK (NPIX/NSPLIT)  // 64 n per block
#define NSUB 32

// ---------- K0: transpose W_f [O,C] -> WfT [C,O] ----------
__global__ void k0_transpose(const float* __restrict__ Wf, float* __restrict__ WfT) {
    int i = blockIdx.x * 256 + threadIdx.x;
    if (i < OCH * CCH) {
        int o = i / CCH, c = i % CCH;
        WfT[c * OCH + o] = Wf[i];
    }
}

// ---------- K1: F[b,o,n] = sum_c WfT[c,o] * x[b,c,n]  (o split in halves) ----------
__global__ __launch_bounds__(256) void k1_F(const float* __restrict__ x,
                                            const float* __restrict__ WfT,
                                            float* __restrict__ F) {
    const int OH = 25;
    int b  = blockIdx.y;
    int oh = blockIdx.z;                        // 0..1
    int n  = blockIdx.x * 256 + threadIdx.x;
    float acc[OH];
#pragma unroll
    for (int j = 0; j < OH; ++j) acc[j] = 0.f;
    const float* xp = x + (size_t)b * CCH * NPIX + n;
    const float* wp = WfT + oh * OH;
    for (int c = 0; c < CCH; c += 4) {
        float x0 = xp[(size_t)(c + 0) * NPIX];
        float x1 = xp[(size_t)(c + 1) * NPIX];
        float x2 = xp[(size_t)(c + 2) * NPIX];
        float x3 = xp[(size_t)(c + 3) * NPIX];
        const float* w0 = wp + (c + 0) * OCH;   // uniform -> s_load
        const float* w1 = wp + (c + 1) * OCH;
        const float* w2 = wp + (c + 2) * OCH;
        const float* w3 = wp + (c + 3) * OCH;
#pragma unroll
        for (int j = 0; j < OH; ++j) {
            acc[j] = fmaf(w0[j], x0, acc[j]);
            acc[j] = fmaf(w1[j], x1, acc[j]);
            acc[j] = fmaf(w2[j], x2, acc[j]);
            acc[j] = fmaf(w3[j], x3, acc[j]);
        }
    }
    float* Fp = F + ((size_t)b * OCH + oh * OH) * NPIX + n;
#pragma unroll
    for (int j = 0; j < OH; ++j) Fp[(size_t)j * NPIX] = acc[j];
}

// ---------- K2: Spart[ks, b*O+o, c] = sum_{n in chunk} F[b,o,n]*x[b,c,n] ----------
__global__ __launch_bounds__(256) void k2_Spart(const float* __restrict__ x,
                                                const float* __restrict__ F,
                                                float* __restrict__ Spart) {
    int ks = blockIdx.x;          // 0..NSPLIT-1
    int b  = blockIdx.y;
    int tid = threadIdx.x;        // = c
    __shared__ float xl[NSUB * (CCH + 1)];  // [n][c] transposed, pad -> conflict-free
    float acc[OCH];
#pragma unroll
    for (int o = 0; o < OCH; ++o) acc[o] = 0.f;
    const float* xb = x + (size_t)b * CCH * NPIX;
    const float* Fb = F + (size_t)b * OCH * NPIX;
    int n0 = ks * KCHUNK;
    int ln = tid & 31, cr = tid >> 5;     // staging roles: lane-n, c-row
    for (int sub = 0; sub < KCHUNK / NSUB; ++sub) {
        int ns = n0 + sub * NSUB;
        __syncthreads();
        // stage x[c][ns..ns+31] -> xl[n][c]
        for (int it = 0; it < CCH / 8; ++it) {
            int c = it * 8 + cr;
            xl[ln * (CCH + 1) + c] = xb[(size_t)c * NPIX + ns + ln];
        }
        __syncthreads();
        for (int ng = 0; ng < NSUB / 4; ++ng) {
            float xv0 = xl[(ng * 4 + 0) * (CCH + 1) + tid];
            float xv1 = xl[(ng * 4 + 1) * (CCH + 1) + tid];
            float xv2 = xl[(ng * 4 + 2) * (CCH + 1) + tid];
            float xv3 = xl[(ng * 4 + 3) * (CCH + 1) + tid];
            const float* fp = Fb + ns + ng * 4;
#pragma unroll
            for (int o = 0; o < OCH; ++o) {
                float4 f = *(const float4*)(fp + (size_t)o * NPIX);  // uniform -> s_load
                acc[o] = fmaf(f.x, xv0, acc[o]);
                acc[o] = fmaf(f.y, xv1, acc[o]);
                acc[o] = fmaf(f.z, xv2, acc[o]);
                acc[o] = fmaf(f.w, xv3, acc[o]);
            }
        }
    }
    float* Sp = Spart + ((size_t)ks * BO + (size_t)b * OCH) * CCH + tid;
#pragma unroll
    for (int o = 0; o < OCH; ++o) Sp[(size_t)o * CCH] = acc[o];
}

// ---------- K2r: reduce partials (4-way split) + softmax over c ----------
__global__ __launch_bounds__(1024) void k2r_softmax(const float* __restrict__ Spart,
                                                    float* __restrict__ S) {
    int row = blockIdx.x;   // b*O+o, 0..199
    int tid = threadIdx.x;  // (c, g)
    int c = tid & 255, g = tid >> 8;           // g in 0..3
    __shared__ float part[4][CCH];
    __shared__ float red[8];
    float v = 0.f;
    const float* p = Spart + ((size_t)(g * (NSPLIT / 4)) * BO + row) * CCH + c;
#pragma unroll 8
    for (int ks = 0; ks < NSPLIT / 4; ++ks)
        v += p[(size_t)ks * BO * CCH];
    part[g][c] = v;
    __syncthreads();
    float vv = 0.f, e = 0.f, m;
    if (tid < 256) {
        vv = part[0][c] + part[1][c] + part[2][c] + part[3][c];
        m = vv;
#pragma unroll
        for (int off = 32; off > 0; off >>= 1) m = fmaxf(m, __shfl_xor(m, off, 64));
        if ((tid & 63) == 0) red[tid >> 6] = m;
    }
    __syncthreads();
    if (tid < 256) {
        m = fmaxf(fmaxf(red[0], red[1]), fmaxf(red[2], red[3]));
        e = expf(vv - m);
        float s = e;
#pragma unroll
        for (int off = 32; off > 0; off >>= 1) s += __shfl_xor(s, off, 64);
        if ((tid & 63) == 0) red[4 + (tid >> 6)] = s;
    }
    __syncthreads();
    if (tid < 256) {
        float tot = red[4] + red[5] + red[6] + red[7];
        S[(size_t)row * CCH + c] = e / tot;
    }
}

// ---------- K3: Mt[b*O+o, d] = sum_c Wbeta[d,c] * S[b*O+o, c] ----------
__global__ __launch_bounds__(256) void k3_M(const float* __restrict__ Wbeta,
                                            const float* __restrict__ S,
                                            float* __restrict__ Mt) {
    int row = blockIdx.x;   // b*O+o
    int d = threadIdx.x;
    const float* srow = S + (size_t)row * CCH;
    const float4* wb = (const float4*)(Wbeta + (size_t)d * CCH);
    float acc = 0.f;
#pragma unroll 4
    for (int cg = 0; cg < CCH / 4; ++cg) {
        float4 w = wb[cg];
        float4 s = *(const float4*)(srow + cg * 4);   // uniform -> s_load
        acc += w.x * s.x + w.y * s.y + w.z * s.z + w.w * s.w;
    }
    Mt[(size_t)row * CCH + d] = acc;
}

// ---------- K4: out[b,d,n] = sum_o Mt[b*O+o, d] * F[b,o,n] + x[b,d,n] ----------
__global__ __launch_bounds__(256) void k4_out(const float* __restrict__ x,
                                              const float* __restrict__ F,
                                              const float* __restrict__ Mt,
                                              float* __restrict__ out) {
    int b  = blockIdx.z;
    int dq = blockIdx.y;                       // 0..3 -> 64 d each
    int n  = blockIdx.x * 256 + threadIdx.x;   // 64 chunks
    float acc[64];
#pragma unroll
    for (int dd = 0; dd < 64; ++dd) acc[dd] = 0.f;
    const float* Fp = F + (size_t)b * OCH * NPIX + n;
    const float* mt = Mt + (size_t)b * OCH * CCH + dq * 64;
#pragma unroll 2
    for (int o = 0; o < OCH; ++o) {
        float fo = Fp[(size_t)o * NPIX];
        const float* m = mt + o * CCH;          // uniform -> s_load
#pragma unroll
        for (int dd = 0; dd < 64; ++dd) acc[dd] = fmaf(m[dd], fo, acc[dd]);
    }
    const float* xp = x + ((size_t)b * CCH + dq * 64) * NPIX + n;
    float* op = out + ((size_t)b * CCH + dq * 64) * NPIX + n;
#pragma unroll
    for (int dd = 0; dd < 64; ++dd)
        __builtin_nontemporal_store(acc[dd] + xp[(size_t)dd * NPIX], &op[(size_t)dd * NPIX]);
}

extern "C" void kernel_launch(void* const* d_in, const int* in_sizes, int n_in,
                              void* d_out, int out_size, void* d_ws, size_t ws_size,
                              hipStream_t stream) {
    const float* x     = (const float*)d_in[0];   // [4,256,128,128]
    const float* Wf    = (const float*)d_in[1];   // [50,256]
    const float* Wbeta = (const float*)d_in[2];   // [256,256]
    float* out = (float*)d_out;

    // ws layout (floats): F [B*O*NPIX] | WfT [C*O] | S [B*O*C] | Mt [B*O*C]
    float* F   = (float*)d_ws;
    float* WfT = F + (size_t)BATCH * OCH * NPIX;
    float* S   = WfT + CCH * OCH;
    float* Mt  = S + (size_t)BO * CCH;
    // S-partials live in d_out (free until K4 overwrites it): NSPLIT*BO*CCH = 13.1M floats <= 16.7M
    float* Spart = out;

    k0_transpose<<<dim3((OCH * CCH + 255) / 256), dim3(256), 0, stream>>>(Wf, WfT);
    k1_F<<<dim3(NPIX / 256, BATCH, 2), dim3(256), 0, stream>>>(x, WfT, F);
    k2_Spart<<<dim3(NSPLIT, BATCH), dim3(256), 0, stream>>>(x, F, Spart);
    k2r_softmax<<<dim3(BO), dim3(1024), 0, stream>>>(Spart, S);
    k3_M<<<dim3(BO), dim3(256), 0, stream>>>(Wbeta, S, Mt);
    k4_out<<<dim3(NPIX / 256, 4, BATCH), dim3(256), 0, stream>>>(x, F, Mt, out);
}

// Round 3
// 242.257 us; speedup vs baseline: 1.5037x; 1.2509x over previous
//
#include <hip/hip_runtime.h>
#include <math.h>

#define CCH 256      // channels C
#define OCH 50       // output channels O
#define NPIX 16384   // H*W
#define BATCH 4
#define BO (BATCH*OCH)   // 200
#define NSPLIT2 128      // K-split for S MFMA GEMM
#define KC2 (NPIX/NSPLIT2)  // 128 pixels per block

typedef _Float16 f16x8 __attribute__((ext_vector_type(8)));
typedef float f32x4 __attribute__((ext_vector_type(4)));

// split fp32 -> f16 hi + f16 lo (x ~= h + l, rel err ~2^-22)
__device__ __forceinline__ void cvt_split(const float4 v0, const float4 v1,
                                          f16x8& h, f16x8& l) {
    float v[8] = {v0.x, v0.y, v0.z, v0.w, v1.x, v1.y, v1.z, v1.w};
#pragma unroll
    for (int j = 0; j < 8; ++j) {
        _Float16 hj = (_Float16)v[j];
        h[j] = hj;
        l[j] = (_Float16)(v[j] - (float)hj);
    }
}

// ---------- K0: transpose W_f [O,C] -> WfT [C,O] ----------
__global__ void k0_transpose(const float* __restrict__ Wf, float* __restrict__ WfT) {
    int i = blockIdx.x * 256 + threadIdx.x;
    if (i < OCH * CCH) {
        int o = i / CCH, c = i % CCH;
        WfT[c * OCH + o] = Wf[i];
    }
}

// ---------- K1: F64[b, o, n] = sum_c WfT[c,o] * x[b,c,n]  (o split in halves) ----------
__global__ __launch_bounds__(256) void k1_F(const float* __restrict__ x,
                                            const float* __restrict__ WfT,
                                            float* __restrict__ F) {
    const int OH = 25;
    int b  = blockIdx.y;
    int oh = blockIdx.z;                        // 0..1
    int n  = blockIdx.x * 256 + threadIdx.x;
    float acc[OH];
#pragma unroll
    for (int j = 0; j < OH; ++j) acc[j] = 0.f;
    const float* xp = x + (size_t)b * CCH * NPIX + n;
    const float* wp = WfT + oh * OH;
    for (int c = 0; c < CCH; c += 4) {
        float x0 = xp[(size_t)(c + 0) * NPIX];
        float x1 = xp[(size_t)(c + 1) * NPIX];
        float x2 = xp[(size_t)(c + 2) * NPIX];
        float x3 = xp[(size_t)(c + 3) * NPIX];
        const float* w0 = wp + (c + 0) * OCH;   // uniform -> s_load
        const float* w1 = wp + (c + 1) * OCH;
        const float* w2 = wp + (c + 2) * OCH;
        const float* w3 = wp + (c + 3) * OCH;
#pragma unroll
        for (int j = 0; j < OH; ++j) {
            acc[j] = fmaf(w0[j], x0, acc[j]);
            acc[j] = fmaf(w1[j], x1, acc[j]);
            acc[j] = fmaf(w2[j], x2, acc[j]);
            acc[j] = fmaf(w3[j], x3, acc[j]);
        }
    }
    float* Fp = F + ((size_t)b * 64 + oh * OH) * NPIX + n;   // F64 layout [B][64][NPIX]
#pragma unroll
    for (int j = 0; j < OH; ++j) Fp[(size_t)j * NPIX] = acc[j];
}

// ---------- K2: MFMA split-f16. Spart[ks][b][64][256] partial logits over 128-pixel chunk ----------
// D[m=o][n=c] = sum_k F[o, n_pix] * x[c, n_pix].  A-frag & B-frag: row = lane&15,
// k = (lane>>4)*8 + j (8 contiguous pixels per lane). C/D: col=lane&15, row=(lane>>4)*4+reg.
__global__ __launch_bounds__(256) void k2_mfma(const float* __restrict__ x,
                                               const float* __restrict__ F,
                                               float* __restrict__ Spart) {
    int ks = blockIdx.x;               // 0..NSPLIT2-1
    int b  = blockIdx.y;
    int wave = threadIdx.x >> 6;       // M-tile 0..3 (o-rows wave*16..+15)
    int lane = threadIdx.x & 63;
    int r16  = lane & 15;
    int kg   = lane >> 4;              // k-group: pixels kg*8..kg*8+7
    int n0   = ks * KC2;

    f32x4 acc[16];
#pragma unroll
    for (int nt = 0; nt < 16; ++nt) acc[nt] = {0.f, 0.f, 0.f, 0.f};

    const float* Ab = F + ((size_t)b * 64 + wave * 16 + r16) * NPIX + n0 + kg * 8;
    const float* Bb = x + ((size_t)b * CCH + r16) * NPIX + n0 + kg * 8;

#pragma unroll
    for (int kk = 0; kk < KC2 / 32; ++kk) {    // 4 k-steps of 32 pixels
        const float* ap = Ab + kk * 32;
        f16x8 ah, al;
        cvt_split(*(const float4*)ap, *(const float4*)(ap + 4), ah, al);
#pragma unroll
        for (int nt = 0; nt < 16; ++nt) {
            const float* bp = Bb + (size_t)nt * 16 * NPIX + kk * 32;
            f16x8 bh, bl;
            cvt_split(*(const float4*)bp, *(const float4*)(bp + 4), bh, bl);
            acc[nt] = __builtin_amdgcn_mfma_f32_16x16x32_f16(ah, bh, acc[nt], 0, 0, 0);
            acc[nt] = __builtin_amdgcn_mfma_f32_16x16x32_f16(ah, bl, acc[nt], 0, 0, 0);
            acc[nt] = __builtin_amdgcn_mfma_f32_16x16x32_f16(al, bh, acc[nt], 0, 0, 0);
        }
    }
    // store: row = wave*16 + kg*4 + r, col = nt*16 + r16
    float* Sp = Spart + (((size_t)ks * BATCH + b) * 64 + wave * 16 + kg * 4) * 256 + r16;
#pragma unroll
    for (int nt = 0; nt < 16; ++nt)
#pragma unroll
        for (int r = 0; r < 4; ++r)
            Sp[(size_t)r * 256 + nt * 16] = acc[nt][r];
}

// ---------- K2r: reduce partials (4-way split) + softmax over c ----------
__global__ __launch_bounds__(1024) void k2r_softmax(const float* __restrict__ Spart,
                                                    float* __restrict__ S) {
    int row = blockIdx.x;   // 0..199
    int b = row / OCH, o = row % OCH;
    int tid = threadIdx.x;
    int c = tid & 255, g = tid >> 8;           // g in 0..3
    __shared__ float part[4][CCH];
    __shared__ float red[8];
    float v = 0.f;
    const size_t ksStride = (size_t)BATCH * 64 * 256;
    const float* p = Spart + ((size_t)(g * (NSPLIT2 / 4)) * BATCH + b) * 64 * 256
                   + (size_t)o * 256 + c;
#pragma unroll 8
    for (int ks = 0; ks < NSPLIT2 / 4; ++ks)
        v += p[ks * ksStride];
    part[g][c] = v;
    __syncthreads();
    float vv = 0.f, e = 0.f, m;
    if (tid < 256) {
        vv = part[0][c] + part[1][c] + part[2][c] + part[3][c];
        m = vv;
#pragma unroll
        for (int off = 32; off > 0; off >>= 1) m = fmaxf(m, __shfl_xor(m, off, 64));
        if ((tid & 63) == 0) red[tid >> 6] = m;
    }
    __syncthreads();
    if (tid < 256) {
        m = fmaxf(fmaxf(red[0], red[1]), fmaxf(red[2], red[3]));
        e = expf(vv - m);
        float s = e;
#pragma unroll
        for (int off = 32; off > 0; off >>= 1) s += __shfl_xor(s, off, 64);
        if ((tid & 63) == 0) red[4 + (tid >> 6)] = s;
    }
    __syncthreads();
    if (tid < 256) {
        float tot = red[4] + red[5] + red[6] + red[7];
        S[(size_t)row * CCH + c] = e / tot;
    }
}

// ---------- K3: Mt[b*O+o, d] = sum_c Wbeta[d,c] * S[b*O+o, c] ----------
__global__ __launch_bounds__(256) void k3_M(const float* __restrict__ Wbeta,
                                            const float* __restrict__ S,
                                            float* __restrict__ Mt) {
    int row = blockIdx.x;   // b*O+o
    int d = threadIdx.x;
    const float* srow = S + (size_t)row * CCH;
    const float4* wb = (const float4*)(Wbeta + (size_t)d * CCH);
    float acc = 0.f;
#pragma unroll 4
    for (int cg = 0; cg < CCH / 4; ++cg) {
        float4 w = wb[cg];
        float4 s = *(const float4*)(srow + cg * 4);   // uniform -> s_load
        acc += w.x * s.x + w.y * s.y + w.z * s.z + w.w * s.w;
    }
    Mt[(size_t)row * CCH + d] = acc;
}

// ---------- K4: out[b,d,n] = sum_o Mt[b*O+o, d] * F64[b,o,n] + x[b,d,n] ----------
__global__ __launch_bounds__(256) void k4_out(const float* __restrict__ x,
                                              const float* __restrict__ F,
                                              const float* __restrict__ Mt,
                                              float* __restrict__ out) {
    int b  = blockIdx.z;
    int dq = blockIdx.y;                       // 0..3 -> 64 d each
    int n  = blockIdx.x * 256 + threadIdx.x;   // 64 chunks
    float acc[64];
#pragma unroll
    for (int dd = 0; dd < 64; ++dd) acc[dd] = 0.f;
    const float* Fp = F + (size_t)b * 64 * NPIX + n;
    const float* mt = Mt + (size_t)b * OCH * CCH + dq * 64;
#pragma unroll 2
    for (int o = 0; o < OCH; ++o) {
        float fo = Fp[(size_t)o * NPIX];
        const float* m = mt + o * CCH;          // uniform -> s_load
#pragma unroll
        for (int dd = 0; dd < 64; ++dd) acc[dd] = fmaf(m[dd], fo, acc[dd]);
    }
    const float* xp = x + ((size_t)b * CCH + dq * 64) * NPIX + n;
    float* op = out + ((size_t)b * CCH + dq * 64) * NPIX + n;
#pragma unroll
    for (int dd = 0; dd < 64; ++dd)
        __builtin_nontemporal_store(acc[dd] + xp[(size_t)dd * NPIX], &op[(size_t)dd * NPIX]);
}

extern "C" void kernel_launch(void* const* d_in, const int* in_sizes, int n_in,
                              void* d_out, int out_size, void* d_ws, size_t ws_size,
                              hipStream_t stream) {
    const float* x     = (const float*)d_in[0];   // [4,256,128,128]
    const float* Wf    = (const float*)d_in[1];   // [50,256]
    const float* Wbeta = (const float*)d_in[2];   // [256,256]
    float* out = (float*)d_out;

    // ws layout (floats): F64 [B*64*NPIX] | WfT [C*O] | S [BO*C] | Mt [BO*C]   (~17.3 MB)
    float* F   = (float*)d_ws;
    float* WfT = F + (size_t)BATCH * 64 * NPIX;
    float* S   = WfT + CCH * OCH;
    float* Mt  = S + (size_t)BO * CCH;
    // S-partials live in d_out (free until K4): NSPLIT2*BATCH*64*256 = 8.4M floats <= 16.7M
    float* Spart = out;

    k0_transpose<<<dim3((OCH * CCH + 255) / 256), dim3(256), 0, stream>>>(Wf, WfT);
    k1_F<<<dim3(NPIX / 256, BATCH, 2), dim3(256), 0, stream>>>(x, WfT, F);
    k2_mfma<<<dim3(NSPLIT2, BATCH), dim3(256), 0, stream>>>(x, F, Spart);
    k2r_softmax<<<dim3(BO), dim3(1024), 0, stream>>>(Spart, S);
    k3_M<<<dim3(BO), dim3(256), 0, stream>>>(Wbeta, S, Mt);
    k4_out<<<dim3(NPIX / 256, 4, BATCH), dim3(256), 0, stream>>>(x, F, Mt, out);
}

// Round 5
// 202.850 us; speedup vs baseline: 1.7958x; 1.1943x over previous
//
#include <hip/hip_runtime.h>
#include <math.h>

#define CCH 256      // channels C
#define OCH 50       // output channels O
#define NPIX 16384   // H*W
#define BATCH 4
#define BO (BATCH*OCH)   // 200
#define NSPLIT2 128      // K-split for S MFMA GEMM
#define KC2 (NPIX/NSPLIT2)  // 128 pixels per ks chunk

typedef _Float16 f16x8 __attribute__((ext_vector_type(8)));
typedef float f32x4 __attribute__((ext_vector_type(4)));
typedef unsigned int uint;
typedef unsigned short ushort;

// split fp32 -> f16 hi + f16 lo (x ~= h + l, rel err ~2^-22)
__device__ __forceinline__ void cvt_split(const float4 v0, const float4 v1,
                                          f16x8& h, f16x8& l) {
    float v[8] = {v0.x, v0.y, v0.z, v0.w, v1.x, v1.y, v1.z, v1.w};
#pragma unroll
    for (int j = 0; j < 8; ++j) {
        _Float16 hj = (_Float16)v[j];
        h[j] = hj;
        l[j] = (_Float16)(v[j] - (float)hj);
    }
}

__device__ __forceinline__ uint packhl(float v) {
    _Float16 h = (_Float16)v;
    _Float16 l = (_Float16)(v - (float)h);
    union { _Float16 f; ushort u; } H, L;
    H.f = h; L.f = l;
    return (uint)H.u | ((uint)L.u << 16);
}

// 8 packed (h|l<<16) words -> f16x8 h-vec and l-vec (v_perm pairs)
__device__ __forceinline__ void unpack8(const uint* w, f16x8& h, f16x8& l) {
    union { uint u[4]; f16x8 v; } H, L;
#pragma unroll
    for (int k = 0; k < 4; ++k) {
        H.u[k] = __builtin_amdgcn_perm(w[2 * k + 1], w[2 * k], 0x05040100u);
        L.u[k] = __builtin_amdgcn_perm(w[2 * k + 1], w[2 * k], 0x07060302u);
    }
    h = H.v; l = L.v;
}

// ---------- K0: pack W_f [50,256] -> Wf16p [64,256] u32 (h|l<<16), zero-padded ----------
__global__ void k0_pack(const float* __restrict__ Wf, uint* __restrict__ Wf16p) {
    int i = blockIdx.x * 256 + threadIdx.x;   // 64*256
    if (i < 64 * CCH) {
        int o = i / CCH;
        float v = (o < OCH) ? Wf[i] : 0.f;
        Wf16p[i] = packhl(v);
    }
}

// ---------- K1: MFMA F[b, o64, n] = sum_c Wf[o,c] * x[b,c,n] ----------
// Block: 64 pixels, all 64 o. Wave w = m-tile (o rows w*16..+15).
// LDS: x tile [32 c][64 pix] packed u32, c-minor with swizzle c' = c ^ ((pix&7)<<2).
__global__ __launch_bounds__(256) void k1_mfma(const float* __restrict__ x,
                                               const uint* __restrict__ Wf16p,
                                               float* __restrict__ F) {
    int b  = blockIdx.y;
    int p0 = blockIdx.x * 64;
    int t  = threadIdx.x;
    int w = t >> 6, lane = t & 63, r16 = lane & 15, kg = lane >> 4;
    __shared__ uint xl[2][32 * 64];

    // staging roles: c on low lane bits (conflict-free transposed writes)
    int cidx = t & 15;          // c row 0..15 (+16 for second reg)
    int pixg = t >> 4;          // pixel group 0..15 (4 pixels each)
    const float* xb = x + ((size_t)b * CCH) * NPIX + p0;

    float4 r0 = *(const float4*)(xb + (size_t)cidx * NPIX + pixg * 4);
    float4 r1 = *(const float4*)(xb + (size_t)(16 + cidx) * NPIX + pixg * 4);

    f32x4 acc[4];
#pragma unroll
    for (int nt = 0; nt < 4; ++nt) acc[nt] = {0.f, 0.f, 0.f, 0.f};

    const uint* Arow = Wf16p + (w * 16 + r16) * CCH;

#pragma unroll
    for (int s = 0; s < 8; ++s) {
        uint* buf = xl[s & 1];
        // write tile s (pre-converted packed h|l), swizzled c-minor
        float v0[4] = {r0.x, r0.y, r0.z, r0.w};
        float v1[4] = {r1.x, r1.y, r1.z, r1.w};
#pragma unroll
        for (int j = 0; j < 4; ++j) {
            int pix = pixg * 4 + j;
            int q = (pix & 7) << 2;
            buf[pix * 32 + (cidx ^ q)]        = packhl(v0[j]);
            buf[pix * 32 + ((16 + cidx) ^ q)] = packhl(v1[j]);
        }
        // issue next tile's global loads early
        if (s < 7) {
            r0 = *(const float4*)(xb + (size_t)((s + 1) * 32 + cidx) * NPIX + pixg * 4);
            r1 = *(const float4*)(xb + (size_t)((s + 1) * 32 + 16 + cidx) * NPIX + pixg * 4);
        }
        __syncthreads();

        // A-frag: 8 packed words from Wf16p row (L2-hot)
        uint aw[8];
        *(uint4*)aw       = *(const uint4*)(Arow + s * 32 + kg * 8);
        *(uint4*)(aw + 4) = *(const uint4*)(Arow + s * 32 + kg * 8 + 4);
        f16x8 Ah, Al;
        unpack8(aw, Ah, Al);

#pragma unroll
        for (int nt = 0; nt < 4; ++nt) {
            int pix = nt * 16 + r16;
            int q = (r16 & 7) << 2;
            uint bw[8];
            *(uint4*)bw       = *(const uint4*)&buf[pix * 32 + ((kg * 8) ^ q)];
            *(uint4*)(bw + 4) = *(const uint4*)&buf[pix * 32 + ((kg * 8 + 4) ^ q)];
            f16x8 Bh, Bl;
            unpack8(bw, Bh, Bl);
            acc[nt] = __builtin_amdgcn_mfma_f32_16x16x32_f16(Ah, Bh, acc[nt], 0, 0, 0);
            acc[nt] = __builtin_amdgcn_mfma_f32_16x16x32_f16(Ah, Bl, acc[nt], 0, 0, 0);
            acc[nt] = __builtin_amdgcn_mfma_f32_16x16x32_f16(Al, Bh, acc[nt], 0, 0, 0);
        }
    }

    // store F: o = w*16 + kg*4 + r, pix = p0 + nt*16 + r16
    float* Fb = F + ((size_t)b * 64 + w * 16 + kg * 4) * NPIX + p0;
#pragma unroll
    for (int nt = 0; nt < 4; ++nt)
#pragma unroll
        for (int r = 0; r < 4; ++r)
            Fb[(size_t)r * NPIX + nt * 16 + r16] = acc[nt][r];
}

// ---------- K2: MFMA split-f16. Spart[ks][b][64][256] partial logits, c-half split ----------
__global__ __launch_bounds__(256) void k2_mfma(const float* __restrict__ x,
                                               const float* __restrict__ F,
                                               float* __restrict__ Spart) {
    int ks = blockIdx.x;               // 0..NSPLIT2-1
    int b  = blockIdx.y;
    int ch = blockIdx.z;               // c half 0..1
    int wave = threadIdx.x >> 6;       // M-tile (o rows wave*16..+15)
    int lane = threadIdx.x & 63;
    int r16  = lane & 15;
    int kg   = lane >> 4;
    int n0   = ks * KC2;

    f32x4 acc[8];
#pragma unroll
    for (int nt = 0; nt < 8; ++nt) acc[nt] = {0.f, 0.f, 0.f, 0.f};

    const float* Ab = F + ((size_t)b * 64 + wave * 16 + r16) * NPIX + n0 + kg * 8;
    const float* Bb = x + ((size_t)b * CCH + ch * 128 + r16) * NPIX + n0 + kg * 8;

#pragma unroll
    for (int kk = 0; kk < KC2 / 32; ++kk) {    // 4 k-steps of 32 pixels
        const float* ap = Ab + kk * 32;
        f16x8 ah, al;
        cvt_split(*(const float4*)ap, *(const float4*)(ap + 4), ah, al);
#pragma unroll
        for (int nt = 0; nt < 8; ++nt) {
            const float* bp = Bb + (size_t)nt * 16 * NPIX + kk * 32;
            f16x8 bh, bl;
            cvt_split(*(const float4*)bp, *(const float4*)(bp + 4), bh, bl);
            acc[nt] = __builtin_amdgcn_mfma_f32_16x16x32_f16(ah, bh, acc[nt], 0, 0, 0);
            acc[nt] = __builtin_amdgcn_mfma_f32_16x16x32_f16(ah, bl, acc[nt], 0, 0, 0);
            acc[nt] = __builtin_amdgcn_mfma_f32_16x16x32_f16(al, bh, acc[nt], 0, 0, 0);
        }
    }
    // store: row = wave*16 + kg*4 + r, col = ch*128 + nt*16 + r16
    float* Sp = Spart + (((size_t)ks * BATCH + b) * 64 + wave * 16 + kg * 4) * 256
              + ch * 128 + r16;
#pragma unroll
    for (int nt = 0; nt < 8; ++nt)
#pragma unroll
        for (int r = 0; r < 4; ++r)
            Sp[(size_t)r * 256 + nt * 16] = acc[nt][r];
}

// ---------- K2r: reduce partials (4-way split) + softmax over c ----------
__global__ __launch_bounds__(1024) void k2r_softmax(const float* __restrict__ Spart,
                                                    float* __restrict__ S) {
    int row = blockIdx.x;   // 0..199
    int b = row / OCH, o = row % OCH;
    int tid = threadIdx.x;
    int c = tid & 255, g = tid >> 8;           // g in 0..3
    __shared__ float part[4][CCH];
    __shared__ float red[8];
    float v = 0.f;
    const size_t ksStride = (size_t)BATCH * 64 * 256;
    const float* p = Spart + ((size_t)(g * (NSPLIT2 / 4)) * BATCH + b) * 64 * 256
                   + (size_t)o * 256 + c;
#pragma unroll 8
    for (int ks = 0; ks < NSPLIT2 / 4; ++ks)
        v += p[ks * ksStride];
    part[g][c] = v;
    __syncthreads();
    float vv = 0.f, e = 0.f, m;
    if (tid < 256) {
        vv = part[0][c] + part[1][c] + part[2][c] + part[3][c];
        m = vv;
#pragma unroll
        for (int off = 32; off > 0; off >>= 1) m = fmaxf(m, __shfl_xor(m, off, 64));
        if ((tid & 63) == 0) red[tid >> 6] = m;
    }
    __syncthreads();
    if (tid < 256) {
        m = fmaxf(fmaxf(red[0], red[1]), fmaxf(red[2], red[3]));
        e = expf(vv - m);
        float s = e;
#pragma unroll
        for (int off = 32; off > 0; off >>= 1) s += __shfl_xor(s, off, 64);
        if ((tid & 63) == 0) red[4 + (tid >> 6)] = s;
    }
    __syncthreads();
    if (tid < 256) {
        float tot = red[4] + red[5] + red[6] + red[7];
        S[(size_t)row * CCH + c] = e / tot;
    }
}

// ---------- K3: Mt[b*O+o, d] = sum_c Wbeta[d,c] * S[b*O+o, c] ----------
__global__ __launch_bounds__(256) void k3_M(const float* __restrict__ Wbeta,
                                            const float* __restrict__ S,
                                            float* __restrict__ Mt) {
    int row = blockIdx.x;   // b*O+o
    int d = threadIdx.x;
    const float* srow = S + (size_t)row * CCH;
    const float4* wb = (const float4*)(Wbeta + (size_t)d * CCH);
    float acc = 0.f;
#pragma unroll 4
    for (int cg = 0; cg < CCH / 4; ++cg) {
        float4 w = wb[cg];
        float4 s = *(const float4*)(srow + cg * 4);   // uniform -> s_load
        acc += w.x * s.x + w.y * s.y + w.z * s.z + w.w * s.w;
    }
    Mt[(size_t)row * CCH + d] = acc;
}

// ---------- K4: out[b,d,n] = sum_o Mt[b*O+o, d] * F64[b,o,n] + x[b,d,n] ----------
__global__ __launch_bounds__(256) void k4_out(const float* __restrict__ x,
                                              const float* __restrict__ F,
                                              const float* __restrict__ Mt,
                                              float* __restrict__ out) {
    int b  = blockIdx.z;
    int dq = blockIdx.y;                       // 0..7 -> 32 d each
    int n  = blockIdx.x * 256 + threadIdx.x;   // 64 chunks
    float acc[32];
#pragma unroll
    for (int dd = 0; dd < 32; ++dd) acc[dd] = 0.f;
    const float* Fp = F + (size_t)b * 64 * NPIX + n;
    const float* mt = Mt + (size_t)b * OCH * CCH + dq * 32;
#pragma unroll 2
    for (int o = 0; o < OCH; ++o) {
        float fo = Fp[(size_t)o * NPIX];
        const float* m = mt + o * CCH;          // uniform -> s_load
#pragma unroll
        for (int dd = 0; dd < 32; ++dd) acc[dd] = fmaf(m[dd], fo, acc[dd]);
    }
    const float* xp = x + ((size_t)b * CCH + dq * 32) * NPIX + n;
    float* op = out + ((size_t)b * CCH + dq * 32) * NPIX + n;
#pragma unroll
    for (int dd = 0; dd < 32; ++dd)
        __builtin_nontemporal_store(acc[dd] + xp[(size_t)dd * NPIX], &op[(size_t)dd * NPIX]);
}

extern "C" void kernel_launch(void* const* d_in, const int* in_sizes, int n_in,
                              void* d_out, int out_size, void* d_ws, size_t ws_size,
                              hipStream_t stream) {
    const float* x     = (const float*)d_in[0];   // [4,256,128,128]
    const float* Wf    = (const float*)d_in[1];   // [50,256]
    const float* Wbeta = (const float*)d_in[2];   // [256,256]
    float* out = (float*)d_out;

    // ws layout (floats): F64 [B*64*NPIX] | Wf16p [64*256 u32] | S [BO*C] | Mt [BO*C]
    float* F     = (float*)d_ws;
    uint*  Wf16p = (uint*)(F + (size_t)BATCH * 64 * NPIX);
    float* S     = (float*)(Wf16p + 64 * CCH);
    float* Mt    = S + (size_t)BO * CCH;
    // S-partials live in d_out (free until K4): 128*4*64*256 = 8.4M floats <= 16.7M
    float* Spart = out;

    k0_pack<<<dim3((64 * CCH + 255) / 256), dim3(256), 0, stream>>>(Wf, Wf16p);
    k1_mfma<<<dim3(NPIX / 64, BATCH), dim3(256), 0, stream>>>(x, Wf16p, F);
    k2_mfma<<<dim3(NSPLIT2, BATCH, 2), dim3(256), 0, stream>>>(x, F, Spart);
    k2r_softmax<<<dim3(BO), dim3(1024), 0, stream>>>(Spart, S);
    k3_M<<<dim3(BO), dim3(256), 0, stream>>>(Wbeta, S, Mt);
    k4_out<<<dim3(NPIX / 256, 8, BATCH), dim3(256), 0, stream>>>(x, F, Mt, out);
}

// Round 6
// 202.163 us; speedup vs baseline: 1.8019x; 1.0034x over previous
//
#include <hip/hip_runtime.h>
#include <math.h>

#define CCH 256      // channels C
#define OCH 50       // output channels O
#define NPIX 16384   // H*W
#define BATCH 4
#define BO (BATCH*OCH)   // 200
#define NSPLIT2 256      // K-split for S MFMA GEMM
#define KC2 (NPIX/NSPLIT2)  // 64 pixels per ks chunk

typedef _Float16 f16x8 __attribute__((ext_vector_type(8)));
typedef float f32x4 __attribute__((ext_vector_type(4)));
typedef unsigned int uint;
typedef unsigned short ushort;

// split fp32 -> f16 hi + f16 lo (x ~= h + l, rel err ~2^-22)
__device__ __forceinline__ void cvt_split(const float4 v0, const float4 v1,
                                          f16x8& h, f16x8& l) {
    float v[8] = {v0.x, v0.y, v0.z, v0.w, v1.x, v1.y, v1.z, v1.w};
#pragma unroll
    for (int j = 0; j < 8; ++j) {
        _Float16 hj = (_Float16)v[j];
        h[j] = hj;
        l[j] = (_Float16)(v[j] - (float)hj);
    }
}

__device__ __forceinline__ uint packhl(float v) {
    _Float16 h = (_Float16)v;
    _Float16 l = (_Float16)(v - (float)h);
    union { _Float16 f; ushort u; } H, L;
    H.f = h; L.f = l;
    return (uint)H.u | ((uint)L.u << 16);
}

// 8 packed (h|l<<16) words -> f16x8 h-vec and l-vec (v_perm pairs)
__device__ __forceinline__ void unpack8(const uint* w, f16x8& h, f16x8& l) {
    union { uint u[4]; f16x8 v; } H, L;
#pragma unroll
    for (int k = 0; k < 4; ++k) {
        H.u[k] = __builtin_amdgcn_perm(w[2 * k + 1], w[2 * k], 0x05040100u);
        L.u[k] = __builtin_amdgcn_perm(w[2 * k + 1], w[2 * k], 0x07060302u);
    }
    h = H.v; l = L.v;
}

// ---------- K0: pack W_f [50,256] -> Wf16p [64,256] u32 (h|l<<16), zero-padded ----------
__global__ void k0_pack(const float* __restrict__ Wf, uint* __restrict__ Wf16p) {
    int i = blockIdx.x * 256 + threadIdx.x;   // 64*256
    if (i < 64 * CCH) {
        int o = i / CCH;
        float v = (o < OCH) ? Wf[i] : 0.f;
        Wf16p[i] = packhl(v);
    }
}

// ---------- K1: MFMA F[b, o64, n] = sum_c Wf[o,c] * x[b,c,n] ----------
// Pipeline per stage: barrier -> issue next-stage loads -> MFMA current (covers
// latency) -> pack+write next stage (consumes loads; barrier drain is then free).
__global__ __launch_bounds__(256) void k1_mfma(const float* __restrict__ x,
                                               const uint* __restrict__ Wf16p,
                                               float* __restrict__ F) {
    int b  = blockIdx.y;
    int p0 = blockIdx.x * 64;
    int t  = threadIdx.x;
    int w = t >> 6, lane = t & 63, r16 = lane & 15, kg = lane >> 4;
    __shared__ uint xl[2][32 * 64];

    int cidx = t & 15;          // c row 0..15 (+16 for second reg)
    int pixg = t >> 4;          // pixel group 0..15 (4 pixels each)
    const float* xb = x + ((size_t)b * CCH) * NPIX + p0;

    float4 r0 = *(const float4*)(xb + (size_t)cidx * NPIX + pixg * 4);
    float4 r1 = *(const float4*)(xb + (size_t)(16 + cidx) * NPIX + pixg * 4);

    f32x4 acc[4];
#pragma unroll
    for (int nt = 0; nt < 4; ++nt) acc[nt] = {0.f, 0.f, 0.f, 0.f};

    const uint* Arow = Wf16p + (w * 16 + r16) * CCH;

    // prologue: pack + write stage 0
    {
        float v0[4] = {r0.x, r0.y, r0.z, r0.w};
        float v1[4] = {r1.x, r1.y, r1.z, r1.w};
#pragma unroll
        for (int j = 0; j < 4; ++j) {
            int pix = pixg * 4 + j;
            int q = (pix & 7) << 2;
            xl[0][pix * 32 + (cidx ^ q)]        = packhl(v0[j]);
            xl[0][pix * 32 + ((16 + cidx) ^ q)] = packhl(v1[j]);
        }
    }
    __syncthreads();

#pragma unroll
    for (int s = 0; s < 8; ++s) {
        // issue next-stage global loads right AFTER the barrier
        if (s < 7) {
            r0 = *(const float4*)(xb + (size_t)((s + 1) * 32 + cidx) * NPIX + pixg * 4);
            r1 = *(const float4*)(xb + (size_t)((s + 1) * 32 + 16 + cidx) * NPIX + pixg * 4);
        }
        // A-frag: 8 packed words from Wf16p row (L2-hot)
        uint aw[8];
        *(uint4*)aw       = *(const uint4*)(Arow + s * 32 + kg * 8);
        *(uint4*)(aw + 4) = *(const uint4*)(Arow + s * 32 + kg * 8 + 4);
        f16x8 Ah, Al;
        unpack8(aw, Ah, Al);

        const uint* buf = xl[s & 1];
#pragma unroll
        for (int nt = 0; nt < 4; ++nt) {
            int pix = nt * 16 + r16;
            int q = (r16 & 7) << 2;
            uint bw[8];
            *(uint4*)bw       = *(const uint4*)&buf[pix * 32 + ((kg * 8) ^ q)];
            *(uint4*)(bw + 4) = *(const uint4*)&buf[pix * 32 + ((kg * 8 + 4) ^ q)];
            f16x8 Bh, Bl;
            unpack8(bw, Bh, Bl);
            acc[nt] = __builtin_amdgcn_mfma_f32_16x16x32_f16(Ah, Bh, acc[nt], 0, 0, 0);
            acc[nt] = __builtin_amdgcn_mfma_f32_16x16x32_f16(Ah, Bl, acc[nt], 0, 0, 0);
            acc[nt] = __builtin_amdgcn_mfma_f32_16x16x32_f16(Al, Bh, acc[nt], 0, 0, 0);
        }
        // pack + write next stage (consumes the prefetch), then barrier
        if (s < 7) {
            float v0[4] = {r0.x, r0.y, r0.z, r0.w};
            float v1[4] = {r1.x, r1.y, r1.z, r1.w};
            uint* nbuf = xl[(s + 1) & 1];
#pragma unroll
            for (int j = 0; j < 4; ++j) {
                int pix = pixg * 4 + j;
                int q = (pix & 7) << 2;
                nbuf[pix * 32 + (cidx ^ q)]        = packhl(v0[j]);
                nbuf[pix * 32 + ((16 + cidx) ^ q)] = packhl(v1[j]);
            }
            __syncthreads();
        }
    }

    // store F: o = w*16 + kg*4 + r, pix = p0 + nt*16 + r16
    float* Fb = F + ((size_t)b * 64 + w * 16 + kg * 4) * NPIX + p0;
#pragma unroll
    for (int nt = 0; nt < 4; ++nt)
#pragma unroll
        for (int r = 0; r < 4; ++r)
            Fb[(size_t)r * NPIX + nt * 16 + r16] = acc[nt][r];
}

// ---------- K2: MFMA split-f16, register-pipelined. Spart[ks][b][64][256] ----------
__global__ __launch_bounds__(256) void k2_mfma(const float* __restrict__ x,
                                               const float* __restrict__ F,
                                               float* __restrict__ Spart) {
    int ks = blockIdx.x;               // 0..NSPLIT2-1
    int b  = blockIdx.y;
    int ch = blockIdx.z;               // c half 0..1
    int wave = threadIdx.x >> 6;       // M-tile (o rows wave*16..+15)
    int lane = threadIdx.x & 63;
    int r16  = lane & 15;
    int kg   = lane >> 4;
    int n0   = ks * KC2;

    // A-frags for both 32-pixel k-steps, hoisted (read once)
    const float* Ab = F + ((size_t)b * 64 + wave * 16 + r16) * NPIX + n0 + kg * 8;
    f16x8 Ah0, Al0, Ah1, Al1;
    cvt_split(*(const float4*)Ab, *(const float4*)(Ab + 4), Ah0, Al0);
    cvt_split(*(const float4*)(Ab + 32), *(const float4*)(Ab + 36), Ah1, Al1);

    const float* Bb = x + ((size_t)b * CCH + ch * 128 + r16) * NPIX + n0 + kg * 8;
    float4 c0 = *(const float4*)(Bb);
    float4 c1 = *(const float4*)(Bb + 4);
    float4 c2 = *(const float4*)(Bb + 32);
    float4 c3 = *(const float4*)(Bb + 36);

    f32x4 acc[8];
#pragma unroll
    for (int nt = 0; nt < 8; ++nt) acc[nt] = {0.f, 0.f, 0.f, 0.f};

#pragma unroll
    for (int nt = 0; nt < 8; ++nt) {
        float4 p0_, p1_, p2_, p3_;
        if (nt < 7) {                          // prefetch next c-tile while computing
            const float* bp = Bb + (size_t)(nt + 1) * 16 * NPIX;
            p0_ = *(const float4*)(bp);
            p1_ = *(const float4*)(bp + 4);
            p2_ = *(const float4*)(bp + 32);
            p3_ = *(const float4*)(bp + 36);
        }
        f16x8 bh, bl;
        cvt_split(c0, c1, bh, bl);
        acc[nt] = __builtin_amdgcn_mfma_f32_16x16x32_f16(Ah0, bh, acc[nt], 0, 0, 0);
        acc[nt] = __builtin_amdgcn_mfma_f32_16x16x32_f16(Ah0, bl, acc[nt], 0, 0, 0);
        acc[nt] = __builtin_amdgcn_mfma_f32_16x16x32_f16(Al0, bh, acc[nt], 0, 0, 0);
        cvt_split(c2, c3, bh, bl);
        acc[nt] = __builtin_amdgcn_mfma_f32_16x16x32_f16(Ah1, bh, acc[nt], 0, 0, 0);
        acc[nt] = __builtin_amdgcn_mfma_f32_16x16x32_f16(Ah1, bl, acc[nt], 0, 0, 0);
        acc[nt] = __builtin_amdgcn_mfma_f32_16x16x32_f16(Al1, bh, acc[nt], 0, 0, 0);
        if (nt < 7) { c0 = p0_; c1 = p1_; c2 = p2_; c3 = p3_; }
    }
    // store: row = wave*16 + kg*4 + r, col = ch*128 + nt*16 + r16
    float* Sp = Spart + (((size_t)ks * BATCH + b) * 64 + wave * 16 + kg * 4) * 256
              + ch * 128 + r16;
#pragma unroll
    for (int nt = 0; nt < 8; ++nt)
#pragma unroll
        for (int r = 0; r < 4; ++r)
            Sp[(size_t)r * 256 + nt * 16] = acc[nt][r];
}

// ---------- K2r: reduce partials (4-way split) + softmax over c ----------
__global__ __launch_bounds__(1024) void k2r_softmax(const float* __restrict__ Spart,
                                                    float* __restrict__ S) {
    int row = blockIdx.x;   // 0..199
    int b = row / OCH, o = row % OCH;
    int tid = threadIdx.x;
    int c = tid & 255, g = tid >> 8;           // g in 0..3
    __shared__ float part[4][CCH];
    __shared__ float red[8];
    float v = 0.f;
    const size_t ksStride = (size_t)BATCH * 64 * 256;
    const float* p = Spart + ((size_t)(g * (NSPLIT2 / 4)) * BATCH + b) * 64 * 256
                   + (size_t)o * 256 + c;
#pragma unroll 8
    for (int ks = 0; ks < NSPLIT2 / 4; ++ks)
        v += p[ks * ksStride];
    part[g][c] = v;
    __syncthreads();
    float vv = 0.f, e = 0.f, m;
    if (tid < 256) {
        vv = part[0][c] + part[1][c] + part[2][c] + part[3][c];
        m = vv;
#pragma unroll
        for (int off = 32; off > 0; off >>= 1) m = fmaxf(m, __shfl_xor(m, off, 64));
        if ((tid & 63) == 0) red[tid >> 6] = m;
    }
    __syncthreads();
    if (tid < 256) {
        m = fmaxf(fmaxf(red[0], red[1]), fmaxf(red[2], red[3]));
        e = expf(vv - m);
        float s = e;
#pragma unroll
        for (int off = 32; off > 0; off >>= 1) s += __shfl_xor(s, off, 64);
        if ((tid & 63) == 0) red[4 + (tid >> 6)] = s;
    }
    __syncthreads();
    if (tid < 256) {
        float tot = red[4] + red[5] + red[6] + red[7];
        S[(size_t)row * CCH + c] = e / tot;
    }
}

// ---------- K3: Mt[b*O+o, d] = sum_c Wbeta[d,c] * S[b*O+o, c] ----------
__global__ __launch_bounds__(256) void k3_M(const float* __restrict__ Wbeta,
                                            const float* __restrict__ S,
                                            float* __restrict__ Mt) {
    int row = blockIdx.x;   // b*O+o
    int d = threadIdx.x;
    const float* srow = S + (size_t)row * CCH;
    const float4* wb = (const float4*)(Wbeta + (size_t)d * CCH);
    float acc = 0.f;
#pragma unroll 4
    for (int cg = 0; cg < CCH / 4; ++cg) {
        float4 w = wb[cg];
        float4 s = *(const float4*)(srow + cg * 4);   // uniform -> s_load
        acc += w.x * s.x + w.y * s.y + w.z * s.z + w.w * s.w;
    }
    Mt[(size_t)row * CCH + d] = acc;
}

// ---------- K4: out[b,d,n] = sum_o Mt[b*O+o, d] * F64[b,o,n] + x[b,d,n] ----------
__global__ __launch_bounds__(256) void k4_out(const float* __restrict__ x,
                                              const float* __restrict__ F,
                                              const float* __restrict__ Mt,
                                              float* __restrict__ out) {
    int b  = blockIdx.z;
    int dq = blockIdx.y;                       // 0..7 -> 32 d each
    int n  = blockIdx.x * 256 + threadIdx.x;   // 64 chunks
    float acc[32];
#pragma unroll
    for (int dd = 0; dd < 32; ++dd) acc[dd] = 0.f;
    const float* Fp = F + (size_t)b * 64 * NPIX + n;
    const float* mt = Mt + (size_t)b * OCH * CCH + dq * 32;
#pragma unroll 2
    for (int o = 0; o < OCH; ++o) {
        float fo = Fp[(size_t)o * NPIX];
        const float* m = mt + o * CCH;          // uniform -> s_load
#pragma unroll
        for (int dd = 0; dd < 32; ++dd) acc[dd] = fmaf(m[dd], fo, acc[dd]);
    }
    const float* xp = x + ((size_t)b * CCH + dq * 32) * NPIX + n;
    float* op = out + ((size_t)b * CCH + dq * 32) * NPIX + n;
#pragma unroll
    for (int dd = 0; dd < 32; ++dd)
        __builtin_nontemporal_store(acc[dd] + xp[(size_t)dd * NPIX], &op[(size_t)dd * NPIX]);
}

extern "C" void kernel_launch(void* const* d_in, const int* in_sizes, int n_in,
                              void* d_out, int out_size, void* d_ws, size_t ws_size,
                              hipStream_t stream) {
    const float* x     = (const float*)d_in[0];   // [4,256,128,128]
    const float* Wf    = (const float*)d_in[1];   // [50,256]
    const float* Wbeta = (const float*)d_in[2];   // [256,256]
    float* out = (float*)d_out;

    // ws layout (floats): F64 [B*64*NPIX] | Wf16p [64*256 u32] | S [BO*C] | Mt [BO*C]
    float* F     = (float*)d_ws;
    uint*  Wf16p = (uint*)(F + (size_t)BATCH * 64 * NPIX);
    float* S     = (float*)(Wf16p + 64 * CCH);
    float* Mt    = S + (size_t)BO * CCH;
    // S-partials live in d_out (free until K4): 256*4*64*256 = 16.78M floats == out_size
    float* Spart = out;

    k0_pack<<<dim3((64 * CCH + 255) / 256), dim3(256), 0, stream>>>(Wf, Wf16p);
    k1_mfma<<<dim3(NPIX / 64, BATCH), dim3(256), 0, stream>>>(x, Wf16p, F);
    k2_mfma<<<dim3(NSPLIT2, BATCH, 2), dim3(256), 0, stream>>>(x, F, Spart);
    k2r_softmax<<<dim3(BO), dim3(1024), 0, stream>>>(Spart, S);
    k3_M<<<dim3(BO), dim3(256), 0, stream>>>(Wbeta, S, Mt);
    k4_out<<<dim3(NPIX / 256, 8, BATCH), dim3(256), 0, stream>>>(x, F, Mt, out);
}

// Round 7
// 193.824 us; speedup vs baseline: 1.8794x; 1.0430x over previous
//
#include <hip/hip_runtime.h>
#include <math.h>

#define CCH 256      // channels C
#define OCH 50       // output channels O
#define NPIX 16384   // H*W
#define BATCH 4
#define BO (BATCH*OCH)   // 200
#define NSPLIT2 256      // K-split (64-pixel chunks) for S GEMM
#define KC2 (NPIX/NSPLIT2)  // 64 pixels per ks chunk

typedef _Float16 f16x8 __attribute__((ext_vector_type(8)));
typedef float f32x4 __attribute__((ext_vector_type(4)));
typedef unsigned int uint;
typedef unsigned short ushort;

// split fp32 -> f16 hi + f16 lo (x ~= h + l, rel err ~2^-22)
__device__ __forceinline__ void cvt_split(const float4 v0, const float4 v1,
                                          f16x8& h, f16x8& l) {
    float v[8] = {v0.x, v0.y, v0.z, v0.w, v1.x, v1.y, v1.z, v1.w};
#pragma unroll
    for (int j = 0; j < 8; ++j) {
        _Float16 hj = (_Float16)v[j];
        h[j] = hj;
        l[j] = (_Float16)(v[j] - (float)hj);
    }
}

__device__ __forceinline__ uint packhl(float v) {
    _Float16 h = (_Float16)v;
    _Float16 l = (_Float16)(v - (float)h);
    union { _Float16 f; ushort u; } H, L;
    H.f = h; L.f = l;
    return (uint)H.u | ((uint)L.u << 16);
}

// 8 packed (h|l<<16) words -> f16x8 h-vec and l-vec (v_perm pairs)
__device__ __forceinline__ void unpack8(const uint* w, f16x8& h, f16x8& l) {
    union { uint u[4]; f16x8 v; } H, L;
#pragma unroll
    for (int k = 0; k < 4; ++k) {
        H.u[k] = __builtin_amdgcn_perm(w[2 * k + 1], w[2 * k], 0x05040100u);
        L.u[k] = __builtin_amdgcn_perm(w[2 * k + 1], w[2 * k], 0x07060302u);
    }
    h = H.v; l = L.v;
}

// ---------- K0: pack W_f [50,256] -> Wf16p [64,256] u32 (h|l<<16), zero-padded ----------
__global__ void k0_pack(const float* __restrict__ Wf, uint* __restrict__ Wf16p) {
    int i = blockIdx.x * 256 + threadIdx.x;   // 64*256
    if (i < 64 * CCH) {
        int o = i / CCH;
        float v = (o < OCH) ? Wf[i] : 0.f;
        Wf16p[i] = packhl(v);
    }
}

// ---------- K12: fused F-GEMM + S-partial GEMM over one 64-pixel chunk ----------
// Stage 1 (k1): F[o64, pix64] = Wf * x, LDS-staged x (c-minor swizzled), 96 MFMA/wave.
// Handoff: per-wave F transpose via LDS [16][68] (C/D lane=pix -> A-frag lane=o).
// Stage 2 (k2): Spart[o64, c256] += F * x^T over the same 64 pixels; B-frags re-read
// x from global (L1/L2-hot), barrier-free, two 8-ct passes (acc 32 VGPR each).
__global__ __launch_bounds__(256, 4) void k12_mfma(const float* __restrict__ x,
                                                   const uint* __restrict__ Wf16p,
                                                   float* __restrict__ F,
                                                   float* __restrict__ Spart) {
    int b  = blockIdx.y;
    int ks = blockIdx.x;        // 0..255
    int p0 = ks * KC2;          // 64-pixel chunk
    int t  = threadIdx.x;
    int w = t >> 6, lane = t & 63, r16 = lane & 15, kg = lane >> 4;
    __shared__ uint xl[2][32 * 64];
    __shared__ float Ft[4][16 * 68];   // per-wave F-transpose area (pad 68: bank-spread)

    int cidx = t & 15;          // staging c row 0..15 (+16 for second reg)
    int pixg = t >> 4;          // staging pixel group 0..15 (4 pixels each)
    const float* xb = x + ((size_t)b * CCH) * NPIX + p0;

    float4 r0 = *(const float4*)(xb + (size_t)cidx * NPIX + pixg * 4);
    float4 r1 = *(const float4*)(xb + (size_t)(16 + cidx) * NPIX + pixg * 4);

    f32x4 acc[4];
#pragma unroll
    for (int nt = 0; nt < 4; ++nt) acc[nt] = {0.f, 0.f, 0.f, 0.f};

    const uint* Arow = Wf16p + (w * 16 + r16) * CCH;

    // prologue: pack + write stage 0
    {
        float v0[4] = {r0.x, r0.y, r0.z, r0.w};
        float v1[4] = {r1.x, r1.y, r1.z, r1.w};
#pragma unroll
        for (int j = 0; j < 4; ++j) {
            int pix = pixg * 4 + j;
            int q = (pix & 7) << 2;
            xl[0][pix * 32 + (cidx ^ q)]        = packhl(v0[j]);
            xl[0][pix * 32 + ((16 + cidx) ^ q)] = packhl(v1[j]);
        }
    }
    __syncthreads();

#pragma unroll
    for (int s = 0; s < 8; ++s) {
        // issue next-stage global loads right AFTER the barrier
        if (s < 7) {
            r0 = *(const float4*)(xb + (size_t)((s + 1) * 32 + cidx) * NPIX + pixg * 4);
            r1 = *(const float4*)(xb + (size_t)((s + 1) * 32 + 16 + cidx) * NPIX + pixg * 4);
        }
        // A-frag: 8 packed words from Wf16p row (L2-hot)
        uint aw[8];
        *(uint4*)aw       = *(const uint4*)(Arow + s * 32 + kg * 8);
        *(uint4*)(aw + 4) = *(const uint4*)(Arow + s * 32 + kg * 8 + 4);
        f16x8 Ah, Al;
        unpack8(aw, Ah, Al);

        const uint* buf = xl[s & 1];
#pragma unroll
        for (int nt = 0; nt < 4; ++nt) {
            int pix = nt * 16 + r16;
            int q = (r16 & 7) << 2;
            uint bw[8];
            *(uint4*)bw       = *(const uint4*)&buf[pix * 32 + ((kg * 8) ^ q)];
            *(uint4*)(bw + 4) = *(const uint4*)&buf[pix * 32 + ((kg * 8 + 4) ^ q)];
            f16x8 Bh, Bl;
            unpack8(bw, Bh, Bl);
            acc[nt] = __builtin_amdgcn_mfma_f32_16x16x32_f16(Ah, Bh, acc[nt], 0, 0, 0);
            acc[nt] = __builtin_amdgcn_mfma_f32_16x16x32_f16(Ah, Bl, acc[nt], 0, 0, 0);
            acc[nt] = __builtin_amdgcn_mfma_f32_16x16x32_f16(Al, Bh, acc[nt], 0, 0, 0);
        }
        // pack + write next stage (consumes the prefetch), then barrier
        if (s < 7) {
            float v0[4] = {r0.x, r0.y, r0.z, r0.w};
            float v1[4] = {r1.x, r1.y, r1.z, r1.w};
            uint* nbuf = xl[(s + 1) & 1];
#pragma unroll
            for (int j = 0; j < 4; ++j) {
                int pix = pixg * 4 + j;
                int q = (pix & 7) << 2;
                nbuf[pix * 32 + (cidx ^ q)]        = packhl(v0[j]);
                nbuf[pix * 32 + ((16 + cidx) ^ q)] = packhl(v1[j]);
            }
            __syncthreads();
        }
    }

    // store F to global (needed by K4): o = w*16 + kg*4 + r, pix = p0 + nt*16 + r16
    float* Fb = F + ((size_t)b * 64 + w * 16 + kg * 4) * NPIX + p0;
#pragma unroll
    for (int nt = 0; nt < 4; ++nt)
#pragma unroll
        for (int r = 0; r < 4; ++r)
            Fb[(size_t)r * NPIX + nt * 16 + r16] = acc[nt][r];

    // handoff: per-wave F transpose (C/D lane=pix -> A-frag lane=o)
    float* ft = Ft[w];
#pragma unroll
    for (int nt = 0; nt < 4; ++nt)
#pragma unroll
        for (int r = 0; r < 4; ++r)
            ft[(kg * 4 + r) * 68 + nt * 16 + r16] = acc[nt][r];
    __syncthreads();

    f16x8 Ah0, Al0, Ah1, Al1;
    {
        const float* fr = ft + r16 * 68;     // o = w*16 + r16, pix k = kk*32 + kg*8 + j
        cvt_split(*(const float4*)(fr + kg * 8), *(const float4*)(fr + kg * 8 + 4), Ah0, Al0);
        cvt_split(*(const float4*)(fr + 32 + kg * 8), *(const float4*)(fr + 32 + kg * 8 + 4), Ah1, Al1);
    }

    // stage 2: Spart rows = wave's 16 o, cols = 256 c (two passes of 8 c-tiles)
    const float* Bb = x + ((size_t)b * CCH) * NPIX + p0 + kg * 8;
#pragma unroll
    for (int half = 0; half < 2; ++half) {
        f32x4 sacc[8];
#pragma unroll
        for (int i = 0; i < 8; ++i) sacc[i] = {0.f, 0.f, 0.f, 0.f};
#pragma unroll
        for (int ct = 0; ct < 8; ++ct) {
            int c = (half * 8 + ct) * 16 + r16;
            const float* bp = Bb + (size_t)c * NPIX;
            f16x8 bh, bl;
            cvt_split(*(const float4*)bp, *(const float4*)(bp + 4), bh, bl);
            sacc[ct] = __builtin_amdgcn_mfma_f32_16x16x32_f16(Ah0, bh, sacc[ct], 0, 0, 0);
            sacc[ct] = __builtin_amdgcn_mfma_f32_16x16x32_f16(Ah0, bl, sacc[ct], 0, 0, 0);
            sacc[ct] = __builtin_amdgcn_mfma_f32_16x16x32_f16(Al0, bh, sacc[ct], 0, 0, 0);
            cvt_split(*(const float4*)(bp + 32), *(const float4*)(bp + 36), bh, bl);
            sacc[ct] = __builtin_amdgcn_mfma_f32_16x16x32_f16(Ah1, bh, sacc[ct], 0, 0, 0);
            sacc[ct] = __builtin_amdgcn_mfma_f32_16x16x32_f16(Ah1, bl, sacc[ct], 0, 0, 0);
            sacc[ct] = __builtin_amdgcn_mfma_f32_16x16x32_f16(Al1, bh, sacc[ct], 0, 0, 0);
        }
        // store: row = w*16 + kg*4 + r, col = half*128 + ct*16 + r16
        float* Sp = Spart + (((size_t)ks * BATCH + b) * 64 + w * 16 + kg * 4) * 256
                  + half * 128 + r16;
#pragma unroll
        for (int ct = 0; ct < 8; ++ct)
#pragma unroll
            for (int r = 0; r < 4; ++r)
                Sp[(size_t)r * 256 + ct * 16] = sacc[ct][r];
    }
}

// ---------- K2r: reduce partials (4-way split) + softmax over c ----------
__global__ __launch_bounds__(1024) void k2r_softmax(const float* __restrict__ Spart,
                                                    float* __restrict__ S) {
    int row = blockIdx.x;   // 0..199
    int b = row / OCH, o = row % OCH;
    int tid = threadIdx.x;
    int c = tid & 255, g = tid >> 8;           // g in 0..3
    __shared__ float part[4][CCH];
    __shared__ float red[8];
    float v = 0.f;
    const size_t ksStride = (size_t)BATCH * 64 * 256;
    const float* p = Spart + ((size_t)(g * (NSPLIT2 / 4)) * BATCH + b) * 64 * 256
                   + (size_t)o * 256 + c;
#pragma unroll 8
    for (int ks = 0; ks < NSPLIT2 / 4; ++ks)
        v += p[ks * ksStride];
    part[g][c] = v;
    __syncthreads();
    float vv = 0.f, e = 0.f, m;
    if (tid < 256) {
        vv = part[0][c] + part[1][c] + part[2][c] + part[3][c];
        m = vv;
#pragma unroll
        for (int off = 32; off > 0; off >>= 1) m = fmaxf(m, __shfl_xor(m, off, 64));
        if ((tid & 63) == 0) red[tid >> 6] = m;
    }
    __syncthreads();
    if (tid < 256) {
        m = fmaxf(fmaxf(red[0], red[1]), fmaxf(red[2], red[3]));
        e = expf(vv - m);
        float s = e;
#pragma unroll
        for (int off = 32; off > 0; off >>= 1) s += __shfl_xor(s, off, 64);
        if ((tid & 63) == 0) red[4 + (tid >> 6)] = s;
    }
    __syncthreads();
    if (tid < 256) {
        float tot = red[4] + red[5] + red[6] + red[7];
        S[(size_t)row * CCH + c] = e / tot;
    }
}

// ---------- K3: Mt[b*O+o, d] = sum_c Wbeta[d,c] * S[b*O+o, c] ----------
__global__ __launch_bounds__(256) void k3_M(const float* __restrict__ Wbeta,
                                            const float* __restrict__ S,
                                            float* __restrict__ Mt) {
    int row = blockIdx.x;   // b*O+o
    int d = threadIdx.x;
    const float* srow = S + (size_t)row * CCH;
    const float4* wb = (const float4*)(Wbeta + (size_t)d * CCH);
    float acc = 0.f;
#pragma unroll 4
    for (int cg = 0; cg < CCH / 4; ++cg) {
        float4 w = wb[cg];
        float4 s = *(const float4*)(srow + cg * 4);   // uniform -> s_load
        acc += w.x * s.x + w.y * s.y + w.z * s.z + w.w * s.w;
    }
    Mt[(size_t)row * CCH + d] = acc;
}

// ---------- K4: out[b,d,n] = sum_o Mt[b*O+o, d] * F64[b,o,n] + x[b,d,n] ----------
__global__ __launch_bounds__(256) void k4_out(const float* __restrict__ x,
                                              const float* __restrict__ F,
                                              const float* __restrict__ Mt,
                                              float* __restrict__ out) {
    int b  = blockIdx.z;
    int dq = blockIdx.y;                       // 0..7 -> 32 d each
    int n  = blockIdx.x * 256 + threadIdx.x;   // 64 chunks
    float acc[32];
#pragma unroll
    for (int dd = 0; dd < 32; ++dd) acc[dd] = 0.f;
    const float* Fp = F + (size_t)b * 64 * NPIX + n;
    const float* mt = Mt + (size_t)b * OCH * CCH + dq * 32;
#pragma unroll 2
    for (int o = 0; o < OCH; ++o) {
        float fo = Fp[(size_t)o * NPIX];
        const float* m = mt + o * CCH;          // uniform -> s_load
#pragma unroll
        for (int dd = 0; dd < 32; ++dd) acc[dd] = fmaf(m[dd], fo, acc[dd]);
    }
    const float* xp = x + ((size_t)b * CCH + dq * 32) * NPIX + n;
    float* op = out + ((size_t)b * CCH + dq * 32) * NPIX + n;
#pragma unroll
    for (int dd = 0; dd < 32; ++dd)
        __builtin_nontemporal_store(acc[dd] + xp[(size_t)dd * NPIX], &op[(size_t)dd * NPIX]);
}

extern "C" void kernel_launch(void* const* d_in, const int* in_sizes, int n_in,
                              void* d_out, int out_size, void* d_ws, size_t ws_size,
                              hipStream_t stream) {
    const float* x     = (const float*)d_in[0];   // [4,256,128,128]
    const float* Wf    = (const float*)d_in[1];   // [50,256]
    const float* Wbeta = (const float*)d_in[2];   // [256,256]
    float* out = (float*)d_out;

    // ws layout (floats): F64 [B*64*NPIX] | Wf16p [64*256 u32] | S [BO*C] | Mt [BO*C]
    float* F     = (float*)d_ws;
    uint*  Wf16p = (uint*)(F + (size_t)BATCH * 64 * NPIX);
    float* S     = (float*)(Wf16p + 64 * CCH);
    float* Mt    = S + (size_t)BO * CCH;
    // S-partials live in d_out (free until K4): 256*4*64*256 = 16.78M floats == out_size
    float* Spart = out;

    k0_pack<<<dim3((64 * CCH + 255) / 256), dim3(256), 0, stream>>>(Wf, Wf16p);
    k12_mfma<<<dim3(NSPLIT2, BATCH), dim3(256), 0, stream>>>(x, Wf16p, F, Spart);
    k2r_softmax<<<dim3(BO), dim3(1024), 0, stream>>>(Spart, S);
    k3_M<<<dim3(BO), dim3(256), 0, stream>>>(Wbeta, S, Mt);
    k4_out<<<dim3(NPIX / 256, 8, BATCH), dim3(256), 0, stream>>>(x, F, Mt, out);
}